// Round 2
// baseline (85.428 us; speedup 1.0000x reference)
//
#include <hip/hip_runtime.h>
#include <stdint.h>

typedef unsigned long long u64;

#define KCAND 9
#define BATCH 16
#define NPRED 30000
#define NGT   64
#define TPB   256                 // 4 waves
#define UNR   8                   // slots per thread per iteration
#define PPT   (TPB * UNR)         // 2048 points per block-iteration
#define NFULL 14                  // 14*2048 = 28672 points, every slot valid
#define TAILB (NFULL * PPT)       // 28672
#define TSLOT 6                   // ceil((30000-28672)/256) = 6 tail slots
#define INITKEY 0x7F800000FFFFFFFFULL
#define FINF  __uint_as_float(0x7F800000u)

__device__ __forceinline__ u64 wave_min_u64(u64 v) {
#pragma unroll
    for (int s = 1; s < 64; s <<= 1) {
        u64 o = __shfl_xor(v, s, 64);
        v = o < v ? o : v;
    }
    return v;
}

// Workspace-free ATSS: one block owns TWO GTs of one image (shared loads),
// two-pass exact top-9 per (wave, GT) with 9th-order-stat threshold.
__global__ __launch_bounds__(TPB, 2) void atss_pair(
    const float* __restrict__ pred,   // [B, N, 4] cxcywh
    const float* __restrict__ gt,     // [B, G, 4] cxcywh
    float* __restrict__ out)          // [4][B*G*K] float32
{
#pragma clang fp contract(off)
    const int tid   = threadIdx.x;
    const int lane  = tid & 63;
    const int wvid  = tid >> 6;
    const int wbase = wvid << 6;

    // grid = 512: bits[2:0]=xcd, bits[7:3]=gt-pair, bit[8]=image-high.
    // XCD k gets images {k, k+8}: per-XCD L2 working set = 2*480KB = 0.96 MB.
    const int bi = blockIdx.x;
    const int b  = (bi & 7) + 8 * (bi >> 8);
    const int gp = (bi >> 3) & 31;
    const int g0 = 2 * gp;

    const float4* gt4 = (const float4*)gt;
    const float4 gA = gt4[b * NGT + g0];
    const float4 gB = gt4[b * NGT + g0 + 1];
    const float aX = gA.x, aY = gA.y;
    const float bX = gB.x, bY = gB.y;
    const float4* pb = (const float4*)pred + (size_t)b * NPRED;

    // ================= pass 1: per-lane running min per GT ==================
    float lmA = FINF, lmB = FINF;
    for (int t = 0; t < NFULL; ++t) {
        const int base = t * PPT + tid;
#pragma unroll
        for (int j = 0; j < UNR; ++j) {
            float4 q = pb[base + j * TPB];
            float dxA = __fsub_rn(aX, q.x), dyA = __fsub_rn(aY, q.y);
            float dA = __fadd_rn(__fmul_rn(dxA, dxA), __fmul_rn(dyA, dyA));
            float dxB = __fsub_rn(bX, q.x), dyB = __fsub_rn(bY, q.y);
            float dB = __fadd_rn(__fmul_rn(dxB, dxB), __fmul_rn(dyB, dyB));
            lmA = fminf(lmA, dA);
            lmB = fminf(lmB, dB);
        }
    }
#pragma unroll
    for (int j = 0; j < TSLOT; ++j) {                 // tail 28672..29999
        const int i = TAILB + j * TPB + tid;
        const bool v = i < NPRED;
        float4 q = pb[v ? i : 0];
        float dxA = __fsub_rn(aX, q.x), dyA = __fsub_rn(aY, q.y);
        float dA = __fadd_rn(__fmul_rn(dxA, dxA), __fmul_rn(dyA, dyA));
        float dxB = __fsub_rn(bX, q.x), dyB = __fsub_rn(bY, q.y);
        float dB = __fadd_rn(__fmul_rn(dxB, dxB), __fmul_rn(dyB, dyB));
        lmA = fminf(lmA, v ? dA : FINF);
        lmB = fminf(lmB, v ? dB : FINF);
    }

    // ====== thresholds: 9th-smallest lane-min per GT (interleaved ILP) ======
    // <=8 points have d < d9  =>  <=8 lane-mins < d9  =>  T >= d9 (safe).
    float vA = lmA, vB = lmB;
    float TA = FINF, TB = FINF;
#pragma unroll
    for (int r = 0; r < KCAND; ++r) {
        float mA = vA, mB = vB;
#pragma unroll
        for (int s = 1; s < 64; s <<= 1) {
            mA = fminf(mA, __shfl_xor(mA, s, 64));
            mB = fminf(mB, __shfl_xor(mB, s, 64));
        }
        TA = mA; TB = mB;
        u64 eA = __ballot(vA == mA);
        if (lane == __ffsll(eA) - 1) vA = FINF;       // remove one instance
        u64 eB = __ballot(vB == mB);
        if (lane == __ffsll(eB) - 1) vB = FINF;
    }

    // ================= pass 2: filtered exact top-9 per GT ==================
    u64 valA = INITKEY, valB = INITKEY;               // sorted in lanes 0..8
    float TfA = TA, TfB = TB;

#define INSERT(DARR, VAL, TF, TBOUND, KI_BASE)                                 \
    {                                                                          \
        u64 pend = __ballot((DARR) <= (TF));                                   \
        while (pend) {                                                         \
            const int src = __ffsll(pend) - 1;                                 \
            pend &= pend - 1;                                                  \
            const unsigned kd = __shfl(__float_as_uint(DARR), src, 64);        \
            const unsigned ki = (unsigned)((KI_BASE) + src);                   \
            const u64 key = ((u64)kd << 32) | ki;                              \
            u64 Tkey = __shfl((VAL), 8, 64);                                   \
            if (key < Tkey) {                                                  \
                const u64 ltm = __ballot((VAL) < key) & 0x1FFULL;              \
                const int pos = __popcll(ltm);                                 \
                const u64 sh = __shfl_up((VAL), 1, 64);                        \
                if (lane < KCAND) {                                            \
                    if (lane == pos)      (VAL) = key;                         \
                    else if (lane > pos)  (VAL) = sh;                          \
                }                                                              \
                Tkey = __shfl((VAL), 8, 64);                                   \
                (TF) = fminf((TBOUND), __uint_as_float((unsigned)(Tkey >> 32)));\
                pend &= __ballot((DARR) <= (TF));                              \
            }                                                                  \
        }                                                                      \
    }

    for (int t = 0; t < NFULL; ++t) {
        const int base = t * PPT + tid;
        float dA[UNR], dB[UNR];
#pragma unroll
        for (int j = 0; j < UNR; ++j) {
            float4 q = pb[base + j * TPB];
            float dxA = __fsub_rn(aX, q.x), dyA = __fsub_rn(aY, q.y);
            dA[j] = __fadd_rn(__fmul_rn(dxA, dxA), __fmul_rn(dyA, dyA));
            float dxB = __fsub_rn(bX, q.x), dyB = __fsub_rn(bY, q.y);
            dB[j] = __fadd_rn(__fmul_rn(dxB, dxB), __fmul_rn(dyB, dyB));
        }
        float mA0 = fminf(fminf(dA[0], dA[1]), fminf(dA[2], dA[3]));
        float mA1 = fminf(fminf(dA[4], dA[5]), fminf(dA[6], dA[7]));
        float mB0 = fminf(fminf(dB[0], dB[1]), fminf(dB[2], dB[3]));
        float mB1 = fminf(fminf(dB[4], dB[5]), fminf(dB[6], dB[7]));
        float dmA = fminf(mA0, mA1), dmB = fminf(mB0, mB1);
        if ((__ballot(dmA <= TfA) | __ballot(dmB <= TfB)) == 0ULL) continue;

#pragma unroll
        for (int j = 0; j < UNR; ++j) {
            INSERT(dA[j], valA, TfA, TA, t * PPT + j * TPB + wbase);
            INSERT(dB[j], valB, TfB, TB, t * PPT + j * TPB + wbase);
        }
    }
    {   // tail 28672..29999 (masked slots -> d=INF, never below finite Tf)
        float dA[TSLOT], dB[TSLOT];
#pragma unroll
        for (int j = 0; j < TSLOT; ++j) {
            const int i = TAILB + j * TPB + tid;
            const bool v = i < NPRED;
            float4 q = pb[v ? i : 0];
            float dxA = __fsub_rn(aX, q.x), dyA = __fsub_rn(aY, q.y);
            float dTA = __fadd_rn(__fmul_rn(dxA, dxA), __fmul_rn(dyA, dyA));
            float dxB = __fsub_rn(bX, q.x), dyB = __fsub_rn(bY, q.y);
            float dTB = __fadd_rn(__fmul_rn(dxB, dxB), __fmul_rn(dyB, dyB));
            dA[j] = v ? dTA : FINF;
            dB[j] = v ? dTB : FINF;
        }
#pragma unroll
        for (int j = 0; j < TSLOT; ++j) {
            INSERT(dA[j], valA, TfA, TA, TAILB + j * TPB + wbase);
            INSERT(dB[j], valB, TfB, TB, TAILB + j * TPB + wbase);
        }
    }
#undef INSERT

    // ---- cross-wave merge through LDS (per GT), epilogue on waves 0/1 ----
    __shared__ u64 smem[2][4 * KCAND];
    if (lane < KCAND) {
        smem[0][wvid * KCAND + lane] = valA;
        smem[1][wvid * KCAND + lane] = valB;
    }
    __syncthreads();

    if (wvid >= 2) return;                 // wave 0 -> g0, wave 1 -> g0+1

    u64 key = (lane < 4 * KCAND) ? smem[wvid][lane] : ~0ULL;
    u64 fin = 0;
#pragma unroll
    for (int k = 0; k < KCAND; ++k) {
        u64 m = wave_min_u64(key);
        if (lane == k) fin = m;
        if (key == m) key = ~0ULL;         // keys unique (disjoint wave domains)
    }

    const int g = g0 + wvid;
    const int w = b * NGT + g;
    const float4 gq = wvid ? gB : gA;
    const float gcx = gq.x, gcy = gq.y;

    const bool active = (lane < KCAND);
    const unsigned idx = active ? (unsigned)(fin & 0xffffffffu) : 0u;

    float4 pbx = pb[idx];

    float gx1 = gcx - 0.5f * gq.z, gy1 = gcy - 0.5f * gq.w;
    float gx2 = gcx + 0.5f * gq.z, gy2 = gcy + 0.5f * gq.w;
    float kx1 = pbx.x - 0.5f * pbx.z, ky1 = pbx.y - 0.5f * pbx.w;
    float kx2 = pbx.x + 0.5f * pbx.z, ky2 = pbx.y + 0.5f * pbx.w;

    float ltx = fmaxf(gx1, kx1), lty = fmaxf(gy1, ky1);
    float rbx = fminf(gx2, kx2), rby = fminf(gy2, ky2);
    float wvd = fmaxf(rbx - ltx, 0.0f);
    float hvd = fmaxf(rby - lty, 0.0f);
    float inter  = wvd * hvd;
    float area_a = (gx2 - gx1) * (gy2 - gy1);
    float area_b = (kx2 - kx1) * (ky2 - ky1);
    float iou = inter / ((area_a + area_b) - inter);

    float v = active ? iou : 0.0f;
    float s = v;
#pragma unroll
    for (int m = 1; m < 64; m <<= 1) s += __shfl_xor(s, m, 64);
    float mean = s / 9.0f;

    float dev = active ? (iou - mean) : 0.0f;
    float ss = dev * dev;
#pragma unroll
    for (int m = 1; m < 64; m <<= 1) ss += __shfl_xor(ss, m, 64);
    float stdv = sqrtf(ss / 8.0f);    // ddof = 1
    float thr = mean + stdv;

    bool inside = (gx1 <= pbx.x) && (pbx.x <= gx2) &&
                  (gy1 <= pbx.y) && (pbx.y <= gy2);
    bool maskk = (iou >= thr) && inside;

    if (active) {
        const size_t chunk = (size_t)BATCH * NGT * KCAND;   // 9216
        const size_t o = (size_t)w * KCAND + lane;
        out[0 * chunk + o] = maskk ? (float)idx : -1.0f;    // pred_idx
        out[1 * chunk + o] = maskk ? (float)g   : -1.0f;    // gt_idx
        out[2 * chunk + o] = maskk ? 1.0f : 0.0f;           // mask
        out[3 * chunk + o] = iou;                           // ious
    }
}

extern "C" void kernel_launch(void* const* d_in, const int* in_sizes, int n_in,
                              void* d_out, int out_size, void* d_ws, size_t ws_size,
                              hipStream_t stream) {
    const float* pred = (const float*)d_in[0];   // [16, 30000, 4] f32
    const float* gtb  = (const float*)d_in[1];   // [16, 64, 4] f32
    float* out = (float*)d_out;
    (void)d_ws; (void)ws_size;                   // workspace untouched: no re-poison fill

    atss_pair<<<BATCH * (NGT / 2), TPB, 0, stream>>>(pred, gtb, out);
}

// Round 4
// 83.620 us; speedup vs baseline: 1.0216x; 1.0216x over previous
//
#include <hip/hip_runtime.h>
#include <stdint.h>

typedef unsigned long long u64;

#define KCAND 9
#define BATCH 16
#define NPRED 30000
#define NGT   64
#define TPB   512                  // 8 waves (known-safe block shape)
#define GTA   4                    // GTs per block
#define UNRF  4                    // float4 loads per thread per iteration
#define PPT   (TPB * UNRF * 2)     // 4096 points per block-iteration
#define NT    8                    // 8 * 4096 = 32768 slots
#define PSTR  32768                // padded points per image (pow2)
#define NF4   (PSTR / 2)           // 16384 float4 per image (compact view)
#define CAP   128                  // candidate slots per GT (expected ~12)
#define INITKEY 0x7F800000FFFFFFFFULL
#define FINF  __uint_as_float(0x7F800000u)
#define SENT  (~0ULL)

__device__ __forceinline__ float wave_min_f(float v) {
#pragma unroll
    for (int s = 1; s < 64; s <<= 1) v = fminf(v, __shfl_xor(v, s, 64));
    return v;
}
__device__ __forceinline__ u64 wave_min_u64(u64 v) {
#pragma unroll
    for (int s = 1; s < 64; s <<= 1) {
        u64 o = __shfl_xor(v, s, 64);
        v = o < v ? o : v;
    }
    return v;
}

// pre-pass: compact xy into [B][PSTR] float2, padded with +inf sentinels.
// (the 268MB workspace re-poison fill is UNCONDITIONAL harness overhead)
__global__ __launch_bounds__(256) void compact_xy(
    const float* __restrict__ pred, float2* __restrict__ xy)
{
    int e = blockIdx.x * 256 + threadIdx.x;   // over BATCH*PSTR (exact multiple)
    int b = e >> 15;                          // PSTR = 32768
    int i = e & (PSTR - 1);
    float2 v;
    if (i < NPRED) {
        float4 p = ((const float4*)pred)[(size_t)b * NPRED + i];
        v = make_float2(p.x, p.y);
    } else {
        v = make_float2(FINF, FINF);
    }
    xy[e] = v;
}

// dist² with explicit rn ops (matches reference selection exactly, contract off)
#define DIST(GX, GY, PX, PY, D)                                              \
    { float _dx = __fsub_rn(GX, PX), _dy = __fsub_rn(GY, PY);                \
      D = __fadd_rn(__fmul_rn(_dx, _dx), __fmul_rn(_dy, _dy)); }

template <bool PADDED>
__global__ __launch_bounds__(TPB, 2) void atss4(
    const float2* __restrict__ xy,    // [B][PSTR] compact (PADDED) or unused
    const float*  __restrict__ pred,  // [B, N, 4] cxcywh
    const float*  __restrict__ gt,    // [B, G, 4] cxcywh
    float* __restrict__ out)          // [4][B*G*K] float32
{
#pragma clang fp contract(off)
    const int tid  = threadIdx.x;
    const int lane = tid & 63;
    const int wv   = tid >> 6;

    // grid = 256: bits[2:0]=xcd(img low3), [6:3]=gt-group, [7]=img-high.
    // Per XCD: 2 images x 256KB compact xy = 0.5MB -> L2-resident.
    const int bi = blockIdx.x;
    const int b  = (bi & 7) + 8 * (bi >> 7);
    const int g0 = ((bi >> 3) & 15) * GTA;

    const float4* gt4 = (const float4*)gt;
    const int w0 = b * NGT + g0;
    const float4 gq0 = gt4[w0],     gq1 = gt4[w0 + 1];
    const float4 gq2 = gt4[w0 + 2], gq3 = gt4[w0 + 3];
    const float aX = gq0.x, aY = gq0.y;
    const float bX = gq1.x, bY = gq1.y;
    const float cX = gq2.x, cY = gq2.y;
    const float dX = gq3.x, dY = gq3.y;

    const float4* p4 = (const float4*)pred + (size_t)b * NPRED;
    const float2* x2 = PADDED ? (xy + (size_t)b * PSTR) : (const float2*)0;
    const float4* x4 = (const float4*)x2;

    __shared__ float tmins[GTA][TPB];   // 8 KB per-thread mins
    __shared__ float tg[GTA];
    __shared__ int   cnt[GTA];
    __shared__ u64   cand[GTA][CAP];    // 4 KB

    if (tid < GTA) cnt[tid] = 0;

    // ============ pass 1: per-THREAD running min per GT =====================
    float lm0 = FINF, lm1 = FINF, lm2 = FINF, lm3 = FINF;
#define P1(PX, PY)                                                           \
    { float d;                                                               \
      DIST(aX, aY, PX, PY, d); lm0 = fminf(lm0, d);                          \
      DIST(bX, bY, PX, PY, d); lm1 = fminf(lm1, d);                          \
      DIST(cX, cY, PX, PY, d); lm2 = fminf(lm2, d);                          \
      DIST(dX, dY, PX, PY, d); lm3 = fminf(lm3, d); }

    if (PADDED) {
        for (int t = 0; t < NT; ++t) {
            const int f0 = t * (PPT / 2) + tid;
#pragma unroll
            for (int k = 0; k < UNRF; ++k) {
                float4 q = x4[f0 + k * TPB];
                P1(q.x, q.y) P1(q.z, q.w)
            }
        }
    } else {
        for (int t = 0; t < NT; ++t) {
#pragma unroll
            for (int j = 0; j < 2 * UNRF; ++j) {
                const int i = t * PPT + j * TPB + tid;
                const bool vv = i < NPRED;
                float4 q = p4[vv ? i : 0];
                float px = vv ? q.x : FINF, py = vv ? q.y : FINF;
                P1(px, py)
            }
        }
    }
#undef P1

    tmins[0][tid] = lm0; tmins[1][tid] = lm1;
    tmins[2][tid] = lm2; tmins[3][tid] = lm3;
    __syncthreads();

    // ===== threshold per GT: 9th-smallest of 512 thread-mins (wave c) =======
    // <=8 points have d < d9 => <=8 threads have min < d9 => T >= d9.
    // Equal-removal drops all copies -> T only looser (larger) -> still valid.
    if (wv < GTA) {
        float a[TPB / 64];
#pragma unroll
        for (int j = 0; j < TPB / 64; ++j) a[j] = tmins[wv][j * 64 + lane];
        float T = FINF;
#pragma unroll
        for (int r = 0; r < KCAND; ++r) {
            float ml = a[0];
#pragma unroll
            for (int j = 1; j < TPB / 64; ++j) ml = fminf(ml, a[j]);
            float m = wave_min_f(ml);
#pragma unroll
            for (int j = 0; j < TPB / 64; ++j) a[j] = (a[j] == m) ? FINF : a[j];
            T = m;
        }
        if (lane == 0) tg[wv] = T;
    }
    __syncthreads();
    const float T0 = tg[0], T1 = tg[1], T2 = tg[2], T3 = tg[3];

    // ============ pass 2: rescan + ballot-collect candidates ================
    // IDXE is an expression in `src` (the contributing lane).
#define COLLECT(H, D, C, IDXE)                                               \
    { u64 bm = __ballot(H);                                                  \
      if (bm) {                                                              \
          int ldr = __ffsll(bm) - 1;                                         \
          int base = 0;                                                      \
          if (lane == ldr) base = atomicAdd(&cnt[C], (int)__popcll(bm));     \
          base = __shfl(base, ldr, 64);                                      \
          if (H) {                                                           \
              int src = lane;                                                \
              int slot = base + (int)__popcll(bm & ((1ULL << lane) - 1ULL)); \
              if (slot < CAP)                                                \
                  cand[C][slot] =                                            \
                      ((u64)__float_as_uint(D) << 32) | (unsigned)(IDXE);    \
          } } }
#define P2(PX, PY, IDXE)                                                     \
    { float e0, e1, e2, e3;                                                  \
      DIST(aX, aY, PX, PY, e0); DIST(bX, bY, PX, PY, e1);                    \
      DIST(cX, cY, PX, PY, e2); DIST(dX, dY, PX, PY, e3);                    \
      bool h0 = e0 <= T0, h1 = e1 <= T1, h2 = e2 <= T2, h3 = e3 <= T3;       \
      if (__ballot(h0 | h1 | h2 | h3)) {                                     \
          COLLECT(h0, e0, 0, IDXE) COLLECT(h1, e1, 1, IDXE)                  \
          COLLECT(h2, e2, 2, IDXE) COLLECT(h3, e3, 3, IDXE)                  \
      } }

    if (PADDED) {
        for (int t = 0; t < NT; ++t) {
            const int f0 = t * (PPT / 2) + tid;
            const int fw = t * (PPT / 2) + (tid - lane);   // wave base (f4 units)
#pragma unroll
            for (int k = 0; k < UNRF; ++k) {
                float4 q = x4[f0 + k * TPB];
                P2(q.x, q.y, 2 * (fw + k * TPB + src))
                P2(q.z, q.w, 2 * (fw + k * TPB + src) + 1)
            }
        }
    } else {
        for (int t = 0; t < NT; ++t) {
#pragma unroll
            for (int j = 0; j < 2 * UNRF; ++j) {
                const int i = t * PPT + j * TPB + tid;
                const int iw = t * PPT + j * TPB + (tid - lane);
                const bool vv = i < NPRED;
                float4 q = p4[vv ? i : 0];
                float px = vv ? q.x : FINF, py = vv ? q.y : FINF;
                P2(px, py, iw + src)
            }
        }
    }
#undef P2
#undef COLLECT
    __syncthreads();

    // ============ exact top-9 selection + epilogue: wave c -> GT c ==========
    if (wv >= GTA) return;
    const int c = wv;
    const float gX = (c == 0) ? aX : (c == 1) ? bX : (c == 2) ? cX : dX;
    const float gY = (c == 0) ? aY : (c == 1) ? bY : (c == 2) ? cY : dY;
    const int n = cnt[c];                       // >=9 guaranteed (T >= d9)

    u64 fin = SENT;
    if (n <= CAP) {
        u64 k0 = (lane < n)      ? cand[c][lane]      : SENT;
        u64 k1 = (lane + 64 < n) ? cand[c][lane + 64] : SENT;
#pragma unroll
        for (int r = 0; r < KCAND; ++r) {
            u64 ml = k0 < k1 ? k0 : k1;
            u64 m = wave_min_u64(ml);
            if (lane == r) fin = m;
            if (k0 == m) k0 = SENT;             // keys unique (idx embedded)
            if (k1 == m) k1 = SENT;
        }
    } else {
        // overflow fallback (never expected on this data): exact sorted-insert
        // over all slots, gated by the valid bound T.  val: sorted lanes 0..8.
        u64 val = INITKEY;
        float Tf = tg[c];
        for (int i0 = 0; i0 < PSTR; i0 += 64) {
            const int i = i0 + lane;
            float px, py;
            if (PADDED) {
                float2 p = x2[i];  px = p.x;  py = p.y;   // pads are +inf
            } else {
                const bool vv = i < NPRED;
                float4 q = p4[vv ? i : 0];
                px = vv ? q.x : FINF;  py = vv ? q.y : FINF;
            }
            float d;  DIST(gX, gY, px, py, d);
            u64 pend = __ballot(d <= Tf);
            while (pend) {
                const int src = __ffsll(pend) - 1;
                pend &= pend - 1;
                const unsigned kd = __shfl(__float_as_uint(d), src, 64);
                const unsigned ki = (unsigned)(i0 + src);
                const u64 key = ((u64)kd << 32) | ki;
                u64 Tkey = __shfl(val, 8, 64);
                if (key < Tkey) {               // wave-uniform
                    const u64 ltm = __ballot(val < key) & 0x1FFULL;
                    const int pos = __popcll(ltm);
                    const u64 sh = __shfl_up(val, 1, 64);
                    if (lane < KCAND) {
                        if (lane == pos)      val = key;
                        else if (lane > pos)  val = sh;
                    }
                    Tkey = __shfl(val, 8, 64);
                    Tf = fminf(tg[c], __uint_as_float((unsigned)(Tkey >> 32)));
                    pend &= __ballot(d <= Tf);
                }
            }
        }
        fin = val;                              // lane r holds r-th smallest
    }

    const int g = g0 + c;
    const int w = b * NGT + g;
    const float4 gq = gt4[w];
    const float gcx = gq.x, gcy = gq.y;

    const bool active = (lane < KCAND);
    const unsigned idx = active ? (unsigned)(fin & 0xffffffffu) : 0u;

    float4 pbx = p4[idx];

    float gx1 = gcx - 0.5f * gq.z, gy1 = gcy - 0.5f * gq.w;
    float gx2 = gcx + 0.5f * gq.z, gy2 = gcy + 0.5f * gq.w;
    float kx1 = pbx.x - 0.5f * pbx.z, ky1 = pbx.y - 0.5f * pbx.w;
    float kx2 = pbx.x + 0.5f * pbx.z, ky2 = pbx.y + 0.5f * pbx.w;

    float ltx = fmaxf(gx1, kx1), lty = fmaxf(gy1, ky1);
    float rbx = fminf(gx2, kx2), rby = fminf(gy2, ky2);
    float wvd = fmaxf(rbx - ltx, 0.0f);
    float hvd = fmaxf(rby - lty, 0.0f);
    float inter  = wvd * hvd;
    float area_a = (gx2 - gx1) * (gy2 - gy1);
    float area_b = (kx2 - kx1) * (ky2 - ky1);
    float iou = inter / ((area_a + area_b) - inter);

    float v = active ? iou : 0.0f;
    float s = v;
#pragma unroll
    for (int m = 1; m < 64; m <<= 1) s += __shfl_xor(s, m, 64);
    float mean = s / 9.0f;

    float dev = active ? (iou - mean) : 0.0f;
    float ss = dev * dev;
#pragma unroll
    for (int m = 1; m < 64; m <<= 1) ss += __shfl_xor(ss, m, 64);
    float stdv = sqrtf(ss / 8.0f);    // ddof = 1
    float thr = mean + stdv;

    bool inside = (gx1 <= pbx.x) && (pbx.x <= gx2) &&
                  (gy1 <= pbx.y) && (pbx.y <= gy2);
    bool maskk = (iou >= thr) && inside;

    if (active) {
        const size_t chunk = (size_t)BATCH * NGT * KCAND;   // 9216
        const size_t o = (size_t)w * KCAND + lane;
        out[0 * chunk + o] = maskk ? (float)idx : -1.0f;    // pred_idx
        out[1 * chunk + o] = maskk ? (float)g   : -1.0f;    // gt_idx
        out[2 * chunk + o] = maskk ? 1.0f : 0.0f;           // mask
        out[3 * chunk + o] = iou;                           // ious
    }
}

extern "C" void kernel_launch(void* const* d_in, const int* in_sizes, int n_in,
                              void* d_out, int out_size, void* d_ws, size_t ws_size,
                              hipStream_t stream) {
    const float* pred = (const float*)d_in[0];   // [16, 30000, 4] f32
    const float* gtb  = (const float*)d_in[1];   // [16, 64, 4] f32
    float* out = (float*)d_out;

    const size_t need = (size_t)BATCH * PSTR * sizeof(float2);   // 4.19 MB
    if (ws_size >= need) {
        float2* xy = (float2*)d_ws;
        compact_xy<<<BATCH * PSTR / 256, 256, 0, stream>>>(pred, xy);
        atss4<true><<<BATCH * (NGT / GTA), TPB, 0, stream>>>(xy, pred, gtb, out);
    } else {
        atss4<false><<<BATCH * (NGT / GTA), TPB, 0, stream>>>(
            nullptr, pred, gtb, out);
    }
}